// Round 1
// baseline (540.709 us; speedup 1.0000x reference)
//
#include <hip/hip_runtime.h>
#include <hip/hip_bf16.h>
#include <stdint.h>

#define BATCH   4096
#define IN_DIM  1024
#define OUT_DIM 1024
#define GRID_G  8
#define NF      17               // 1 (silu) + 8 cos + 8 sin
#define KDIM    (IN_DIM * NF)    // 17408

typedef __bf16 bf16x8 __attribute__((ext_vector_type(8)));
typedef float  f32x4  __attribute__((ext_vector_type(4)));

// ---------------------------------------------------------------------------
// Kernel 1: features F[b, k], k = f*IN_DIM + i
//   f=0: silu(x); f=1..8: cos(f*x); f=9..16: sin((f-8)*x)
// One thread per (b, i). Harmonics via angle-addition recurrence
// (2 transcendentals instead of 16).
// ---------------------------------------------------------------------------
__global__ void build_features(const float* __restrict__ x, __bf16* __restrict__ A) {
    int idx = blockIdx.x * blockDim.x + threadIdx.x;   // b*IN_DIM + i
    int b = idx >> 10;
    int i = idx & 1023;
    float xv = x[idx];
    float sil = xv / (1.f + __expf(-xv));
    float s1, c1;
    __sincosf(xv, &s1, &c1);
    __bf16* base = A + (size_t)b * KDIM + i;
    base[0] = (__bf16)sil;
    float ck = c1, sk = s1;
#pragma unroll
    for (int g = 1; g <= GRID_G; ++g) {
        base[(size_t)g * IN_DIM]            = (__bf16)ck;
        base[(size_t)(GRID_G + g) * IN_DIM] = (__bf16)sk;
        float cn = ck * c1 - sk * s1;
        float sn = sk * c1 + ck * s1;
        ck = cn; sk = sn;
    }
}

// ---------------------------------------------------------------------------
// Kernel 2: folded weights W[o, k], k = f*IN_DIM + i  (matches feature layout)
//   f=0: scale_base; f=1..8: ss*coeff[0,o,i,f-1]; f=9..16: ss*coeff[1,o,i,f-9]
// ---------------------------------------------------------------------------
__global__ void fold_weights(const float* __restrict__ sb, const float* __restrict__ ss,
                             const float* __restrict__ coeff, __bf16* __restrict__ W) {
    int idx = blockIdx.x * blockDim.x + threadIdx.x;   // o*IN_DIM + i
    float s = ss[idx];
    __bf16* wb = W + ((size_t)(idx >> 10)) * KDIM + (idx & 1023);
    wb[0] = (__bf16)sb[idx];
    const float4* c0 = (const float4*)(coeff + (size_t)idx * GRID_G);
    const float4* c1 = (const float4*)(coeff + ((size_t)idx + (size_t)OUT_DIM * IN_DIM) * GRID_G);
    float4 a0 = c0[0], a1 = c0[1];
    float4 b0 = c1[0], b1 = c1[1];
    wb[(size_t)1  * IN_DIM] = (__bf16)(s * a0.x);
    wb[(size_t)2  * IN_DIM] = (__bf16)(s * a0.y);
    wb[(size_t)3  * IN_DIM] = (__bf16)(s * a0.z);
    wb[(size_t)4  * IN_DIM] = (__bf16)(s * a0.w);
    wb[(size_t)5  * IN_DIM] = (__bf16)(s * a1.x);
    wb[(size_t)6  * IN_DIM] = (__bf16)(s * a1.y);
    wb[(size_t)7  * IN_DIM] = (__bf16)(s * a1.z);
    wb[(size_t)8  * IN_DIM] = (__bf16)(s * a1.w);
    wb[(size_t)9  * IN_DIM] = (__bf16)(s * b0.x);
    wb[(size_t)10 * IN_DIM] = (__bf16)(s * b0.y);
    wb[(size_t)11 * IN_DIM] = (__bf16)(s * b0.z);
    wb[(size_t)12 * IN_DIM] = (__bf16)(s * b0.w);
    wb[(size_t)13 * IN_DIM] = (__bf16)(s * b1.x);
    wb[(size_t)14 * IN_DIM] = (__bf16)(s * b1.y);
    wb[(size_t)15 * IN_DIM] = (__bf16)(s * b1.z);
    wb[(size_t)16 * IN_DIM] = (__bf16)(s * b1.w);
}

// ---------------------------------------------------------------------------
// Kernel 3: C[M,N] = A[M,K] * B[N,K]^T  (m97 structure: 128x128 tile, BK=32,
// 256 threads = 4 waves in 2x2, global_load_lds width-16 staging,
// 16x mfma_f32_16x16x32_bf16 per K-step)
// ---------------------------------------------------------------------------
__global__ __launch_bounds__(256) void gemm_bt(const __bf16* __restrict__ A,
                                               const __bf16* __restrict__ B,
                                               float* __restrict__ C) {
    __shared__ __align__(16) __bf16 As[128 * 32];
    __shared__ __align__(16) __bf16 Bs[128 * 32];
    const int tid = threadIdx.x;
    const int w   = tid >> 6;      // wave 0..3
    const int l   = tid & 63;      // lane
    const int bm  = blockIdx.x;    // M/128 = 32
    const int bn  = blockIdx.y;    // N/128 = 8
    const int wm  = w & 1;
    const int wn  = w >> 1;

    f32x4 acc[4][4] = {};

    const int lr = l >> 2;         // 0..15: row within 16-row group
    const int lc = (l & 3) * 8;    // 0,8,16,24: element offset in row (16 B)
    const __bf16* Ag = A + (size_t)(bm * 128) * KDIM;
    const __bf16* Bg = B + (size_t)(bn * 128) * KDIM;

    for (int k0 = 0; k0 < KDIM; k0 += 32) {
        // stage A-tile and B-tile (128x32 bf16 each); wave w fills rows
        // [q*64 + w*16, +16); per-lane LDS dest = uniform base + lane*16B
#pragma unroll
        for (int q = 0; q < 2; ++q) {
            int row = q * 64 + w * 16 + lr;
            __builtin_amdgcn_global_load_lds(
                (const uint32_t*)(Ag + (size_t)row * KDIM + k0 + lc),
                (uint32_t*)(As + q * 2048 + w * 512), 16, 0, 0);
            __builtin_amdgcn_global_load_lds(
                (const uint32_t*)(Bg + (size_t)row * KDIM + k0 + lc),
                (uint32_t*)(Bs + q * 2048 + w * 512), 16, 0, 0);
        }
        __syncthreads();

        const int koff = (l >> 4) * 8;   // lane group -> K offset
        const int lm   = l & 15;
        bf16x8 af[4], bfr[4];
#pragma unroll
        for (int i = 0; i < 4; ++i)
            af[i] = *(const bf16x8*)(As + (wm * 64 + i * 16 + lm) * 32 + koff);
#pragma unroll
        for (int j = 0; j < 4; ++j)
            bfr[j] = *(const bf16x8*)(Bs + (wn * 64 + j * 16 + lm) * 32 + koff);
#pragma unroll
        for (int i = 0; i < 4; ++i)
#pragma unroll
            for (int j = 0; j < 4; ++j)
                acc[i][j] = __builtin_amdgcn_mfma_f32_16x16x32_bf16(af[i], bfr[j], acc[i][j], 0, 0, 0);
        __syncthreads();
    }

    // epilogue: C/D layout col = lane&15, row = (lane>>4)*4 + reg
    const int row0 = bm * 128 + wm * 64 + ((l >> 4) * 4);
    const int col0 = bn * 128 + wn * 64 + (l & 15);
#pragma unroll
    for (int i = 0; i < 4; ++i)
#pragma unroll
        for (int j = 0; j < 4; ++j) {
#pragma unroll
            for (int r = 0; r < 4; ++r)
                C[(size_t)(row0 + i * 16 + r) * OUT_DIM + col0 + j * 16] = acc[i][j][r];
        }
}

// ---------------------------------------------------------------------------
extern "C" void kernel_launch(void* const* d_in, const int* in_sizes, int n_in,
                              void* d_out, int out_size, void* d_ws, size_t ws_size,
                              hipStream_t stream) {
    const float* x     = (const float*)d_in[0];   // (B, I)
    const float* sb    = (const float*)d_in[1];   // (O, I)
    const float* ss    = (const float*)d_in[2];   // (O, I)
    const float* coeff = (const float*)d_in[3];   // (2, O, I, G)
    float* out = (float*)d_out;                   // (B, O)

    __bf16* A = (__bf16*)d_ws;                        // BATCH * KDIM bf16 = 142.6 MB
    __bf16* W = A + (size_t)BATCH * KDIM;             // OUT_DIM * KDIM bf16 = 35.7 MB

    hipLaunchKernelGGL(build_features, dim3((BATCH * IN_DIM) / 256), dim3(256), 0, stream, x, A);
    hipLaunchKernelGGL(fold_weights, dim3((OUT_DIM * IN_DIM) / 256), dim3(256), 0, stream,
                       sb, ss, coeff, W);
    hipLaunchKernelGGL(gemm_bt, dim3(BATCH / 128, OUT_DIM / 128), dim3(256), 0, stream, A, W, out);
}

// Round 2
// 397.212 us; speedup vs baseline: 1.3613x; 1.3613x over previous
//
#include <hip/hip_runtime.h>
#include <hip/hip_bf16.h>
#include <stdint.h>

#define BATCH   4096
#define IN_DIM  1024
#define OUT_DIM 1024
#define GRID_G  8
#define NF      17               // 1 (silu) + 8 cos + 8 sin
#define KDIM    (IN_DIM * NF)    // 17408
#define SPLITK  4
#define KCHUNK  (KDIM / SPLITK)  // 4352 (136 k-steps of 32)

typedef __bf16 bf16x8 __attribute__((ext_vector_type(8)));
typedef float  f32x4  __attribute__((ext_vector_type(4)));

// ---------------------------------------------------------------------------
// Kernel 1: features F[b, k], k = f*IN_DIM + i
//   f=0: silu(x); f=1..8: cos(f*x); f=9..16: sin((f-8)*x)
// One thread per (b, 8 consecutive i). All stores are 16 B bf16x8.
// Harmonics via angle-addition recurrence (2 transcendentals / element).
// ---------------------------------------------------------------------------
__global__ void build_features(const float* __restrict__ x, __bf16* __restrict__ A) {
    int t  = blockIdx.x * blockDim.x + threadIdx.x;   // over BATCH*IN_DIM/8
    int b  = t >> 7;                                  // 128 groups of 8 per row
    int i0 = (t & 127) * 8;
    const float4* xp = (const float4*)(x + (size_t)b * IN_DIM + i0);
    float4 x0 = xp[0], x1 = xp[1];
    float xv[8] = {x0.x, x0.y, x0.z, x0.w, x1.x, x1.y, x1.z, x1.w};

    float c1[8], s1[8], ck[8], sk[8];
    bf16x8 v;
    __bf16* base = A + (size_t)b * KDIM + i0;

#pragma unroll
    for (int j = 0; j < 8; ++j) {
        float sil = xv[j] / (1.f + __expf(-xv[j]));
        v[j] = (__bf16)sil;
        __sincosf(xv[j], &s1[j], &c1[j]);
        ck[j] = c1[j]; sk[j] = s1[j];
    }
    *(bf16x8*)base = v;

#pragma unroll
    for (int g = 1; g <= GRID_G; ++g) {
        bf16x8 vc, vs;
#pragma unroll
        for (int j = 0; j < 8; ++j) {
            vc[j] = (__bf16)ck[j];
            vs[j] = (__bf16)sk[j];
            float cn = ck[j] * c1[j] - sk[j] * s1[j];
            float sn = sk[j] * c1[j] + ck[j] * s1[j];
            ck[j] = cn; sk[j] = sn;
        }
        *(bf16x8*)(base + (size_t)g * IN_DIM)            = vc;
        *(bf16x8*)(base + (size_t)(GRID_G + g) * IN_DIM) = vs;
    }
}

// ---------------------------------------------------------------------------
// Kernel 2: folded weights W[o, k], k = f*IN_DIM + i  (matches feature layout)
// One thread per (o, 8 consecutive i). 16 B stores; coalesced float4 coeff reads.
// ---------------------------------------------------------------------------
__global__ void fold_weights(const float* __restrict__ sb, const float* __restrict__ ss,
                             const float* __restrict__ coeff, __bf16* __restrict__ W) {
    int t  = blockIdx.x * blockDim.x + threadIdx.x;   // over OUT_DIM*IN_DIM/8
    int o  = t >> 7;
    int i0 = (t & 127) * 8;
    size_t oi = (size_t)o * IN_DIM + i0;

    float s[8];
    {
        const float4* sp = (const float4*)(ss + oi);
        float4 s0 = sp[0], s1 = sp[1];
        s[0]=s0.x; s[1]=s0.y; s[2]=s0.z; s[3]=s0.w;
        s[4]=s1.x; s[5]=s1.y; s[6]=s1.z; s[7]=s1.w;
    }
    __bf16* wb = W + (size_t)o * KDIM + i0;
    {
        const float4* bp = (const float4*)(sb + oi);
        float4 b0 = bp[0], b1 = bp[1];
        float bv[8] = {b0.x, b0.y, b0.z, b0.w, b1.x, b1.y, b1.z, b1.w};
        bf16x8 v;
#pragma unroll
        for (int j = 0; j < 8; ++j) v[j] = (__bf16)bv[j];
        *(bf16x8*)wb = v;
    }

    // two coeff planes (cos: f=1..8, sin: f=9..16)
#pragma unroll
    for (int p = 0; p < 2; ++p) {
        const float* cp = coeff + ((size_t)p * OUT_DIM * IN_DIM + oi) * GRID_G;
        float c[8][8];                     // [j][g]
#pragma unroll
        for (int j = 0; j < 8; ++j) {
            const float4* cj = (const float4*)(cp + (size_t)j * GRID_G);
            float4 a0 = cj[0], a1 = cj[1];
            c[j][0]=a0.x; c[j][1]=a0.y; c[j][2]=a0.z; c[j][3]=a0.w;
            c[j][4]=a1.x; c[j][5]=a1.y; c[j][6]=a1.z; c[j][7]=a1.w;
        }
#pragma unroll
        for (int g = 0; g < GRID_G; ++g) {
            bf16x8 v;
#pragma unroll
            for (int j = 0; j < 8; ++j) v[j] = (__bf16)(s[j] * c[j][g]);
            *(bf16x8*)(wb + (size_t)(1 + p * GRID_G + g) * IN_DIM) = v;
        }
    }
}

// ---------------------------------------------------------------------------
// Kernel 3: C[M,N] += A[M,K_chunk] * B[N,K_chunk]^T, split-K x4.
// 128x128 tile, BK=32, 256 threads = 4 waves in 2x2, global_load_lds width-16,
// 16x mfma_f32_16x16x32_bf16 per K-step. Epilogue: HW f32 atomic add.
// Grid 32x8x4 = 1024 blocks -> 4 blocks/CU (barrier-drain hiding per m103).
// ---------------------------------------------------------------------------
__global__ __launch_bounds__(256) void gemm_bt(const __bf16* __restrict__ A,
                                               const __bf16* __restrict__ B,
                                               float* __restrict__ C) {
    __shared__ __align__(16) __bf16 As[128 * 32];
    __shared__ __align__(16) __bf16 Bs[128 * 32];
    const int tid = threadIdx.x;
    const int w   = tid >> 6;      // wave 0..3
    const int l   = tid & 63;      // lane
    const int bm  = blockIdx.x;    // M/128 = 32
    const int bn  = blockIdx.y;    // N/128 = 8
    const int kz  = blockIdx.z;    // split-K chunk
    const int wm  = w & 1;
    const int wn  = w >> 1;

    f32x4 acc[4][4] = {};

    const int lr = l >> 2;         // 0..15: row within 16-row group
    const int lc = (l & 3) * 8;    // 0,8,16,24: element offset in row (16 B)
    const __bf16* Ag = A + (size_t)(bm * 128) * KDIM;
    const __bf16* Bg = B + (size_t)(bn * 128) * KDIM;
    const int kbeg = kz * KCHUNK;
    const int kend = kbeg + KCHUNK;

    for (int k0 = kbeg; k0 < kend; k0 += 32) {
        // stage A-tile and B-tile (128x32 bf16 each); wave w fills rows
        // [q*64 + w*16, +16); per-lane LDS dest = uniform base + lane*16B
#pragma unroll
        for (int q = 0; q < 2; ++q) {
            int row = q * 64 + w * 16 + lr;
            __builtin_amdgcn_global_load_lds(
                (const uint32_t*)(Ag + (size_t)row * KDIM + k0 + lc),
                (uint32_t*)(As + q * 2048 + w * 512), 16, 0, 0);
            __builtin_amdgcn_global_load_lds(
                (const uint32_t*)(Bg + (size_t)row * KDIM + k0 + lc),
                (uint32_t*)(Bs + q * 2048 + w * 512), 16, 0, 0);
        }
        __syncthreads();

        const int koff = (l >> 4) * 8;   // lane group -> K offset
        const int lm   = l & 15;
        bf16x8 af[4], bfr[4];
#pragma unroll
        for (int i = 0; i < 4; ++i)
            af[i] = *(const bf16x8*)(As + (wm * 64 + i * 16 + lm) * 32 + koff);
#pragma unroll
        for (int j = 0; j < 4; ++j)
            bfr[j] = *(const bf16x8*)(Bs + (wn * 64 + j * 16 + lm) * 32 + koff);
#pragma unroll
        for (int i = 0; i < 4; ++i)
#pragma unroll
            for (int j = 0; j < 4; ++j)
                acc[i][j] = __builtin_amdgcn_mfma_f32_16x16x32_bf16(af[i], bfr[j], acc[i][j], 0, 0, 0);
        __syncthreads();
    }

    // epilogue: C/D layout col = lane&15, row = (lane>>4)*4 + reg
    const int row0 = bm * 128 + wm * 64 + ((l >> 4) * 4);
    const int col0 = bn * 128 + wn * 64 + (l & 15);
#pragma unroll
    for (int i = 0; i < 4; ++i)
#pragma unroll
        for (int j = 0; j < 4; ++j) {
#pragma unroll
            for (int r = 0; r < 4; ++r)
                unsafeAtomicAdd(&C[(size_t)(row0 + i * 16 + r) * OUT_DIM + col0 + j * 16],
                                acc[i][j][r]);
        }
}

// ---------------------------------------------------------------------------
extern "C" void kernel_launch(void* const* d_in, const int* in_sizes, int n_in,
                              void* d_out, int out_size, void* d_ws, size_t ws_size,
                              hipStream_t stream) {
    const float* x     = (const float*)d_in[0];   // (B, I)
    const float* sb    = (const float*)d_in[1];   // (O, I)
    const float* ss    = (const float*)d_in[2];   // (O, I)
    const float* coeff = (const float*)d_in[3];   // (2, O, I, G)
    float* out = (float*)d_out;                   // (B, O)

    __bf16* A = (__bf16*)d_ws;                        // BATCH * KDIM bf16 = 142.6 MB
    __bf16* W = A + (size_t)BATCH * KDIM;             // OUT_DIM * KDIM bf16 = 35.7 MB

    hipLaunchKernelGGL(build_features, dim3((BATCH * IN_DIM / 8) / 256), dim3(256), 0, stream, x, A);
    hipLaunchKernelGGL(fold_weights, dim3((OUT_DIM * IN_DIM / 8) / 256), dim3(256), 0, stream,
                       sb, ss, coeff, W);
    hipMemsetAsync(out, 0, (size_t)BATCH * OUT_DIM * sizeof(float), stream);
    hipLaunchKernelGGL(gemm_bt, dim3(BATCH / 128, OUT_DIM / 128, SPLITK), dim3(256), 0, stream,
                       A, W, out);
}